// Round 24
// baseline (146.945 us; speedup 1.0000x reference)
//
#include <hip/hip_runtime.h>

#define SEQ 4096
#define DMODEL 1024
#define HEADS 16
#define HD 64
#define NQKV 3072

typedef __attribute__((ext_vector_type(8))) __bf16 bf16x8;
typedef __attribute__((ext_vector_type(4))) __bf16 bf16x4;
typedef __attribute__((ext_vector_type(8))) short short8;
typedef __attribute__((ext_vector_type(4))) float f32x4;
typedef __attribute__((ext_vector_type(16))) float f32x16;
typedef __attribute__((ext_vector_type(4))) unsigned int u32x4;

__device__ __forceinline__ unsigned short f2bf(float f) {
    unsigned u = __builtin_bit_cast(unsigned, f);
    return (unsigned short)((u + 0x7fffu + ((u >> 16) & 1u)) >> 16);
}
__device__ __forceinline__ float bf2f(unsigned short h) {
    return __builtin_bit_cast(float, (unsigned)h << 16);
}
__device__ __forceinline__ unsigned cvt_pk_bf16(float lo, float hi) {
    unsigned r;
    asm("v_cvt_pk_bf16_f32 %0, %1, %2" : "=v"(r) : "v"(lo), "v"(hi));
    return r;
}

__device__ __forceinline__ void gload16(const void* g, void* l) {
    __builtin_amdgcn_global_load_lds(
        (const __attribute__((address_space(1))) unsigned int*)g,
        (__attribute__((address_space(3))) unsigned int*)l, 16, 0, 0);
}

// per-head task table, LPT. bits0-4 qtile(256-row), bits5-6 piece, bit7 split-flag.
// qt14,15: 4 pieces; qt5..13: 2 pieces; qt0..4 unsplit. 31 tasks/head, 62/XCD.
#define T2(qt, p) (0x80 | ((p) << 5) | (qt))
__device__ __constant__ unsigned char TASKS[31] = {
    T2(15,0), T2(15,1), T2(15,2), T2(15,3),
    T2(13,0), T2(13,1), T2(14,0), T2(14,1),
    T2(12,0), T2(12,1), T2(14,2), T2(14,3),
    T2(11,0), T2(11,1), T2(10,0), T2(10,1),
    T2(9,0),  T2(9,1),  T2(8,0),  T2(8,1),
    T2(7,0),  T2(7,1),  4,        T2(6,0),
    T2(6,1),  T2(5,0),  T2(5,1),  3, 2, 1, 0
};

// ---------------- fp32 -> bf16 convert + RoPE tables + qcnt zero ----------------
__global__ void f2bf_all(const float* __restrict__ x, const float* __restrict__ wqkv,
                         const float* __restrict__ wo, const int* __restrict__ pos,
                         unsigned short* __restrict__ dst,
                         float* __restrict__ csT, float* __restrict__ snT,
                         int* __restrict__ qcnt) {
    const int N0 = SEQ * DMODEL / 4;
    const int N1 = N0 + NQKV * DMODEL / 4;
    const int NT = N1 + DMODEL * DMODEL / 4;
    int i = blockIdx.x * 256 + threadIdx.x;
    int stride = gridDim.x * 256;
    if (blockIdx.x == 0 && threadIdx.x < 16) qcnt[threadIdx.x] = 0;  // qcnt OUTSIDE dst region
    for (; i < NT; i += stride) {
        const float4* src;
        if (i < N0)      src = reinterpret_cast<const float4*>(x) + i;
        else if (i < N1) src = reinterpret_cast<const float4*>(wqkv) + (i - N0);
        else             src = reinterpret_cast<const float4*>(wo) + (i - N1);
        float4 f = *src;
        ushort4 o;
        o.x = f2bf(f.x); o.y = f2bf(f.y); o.z = f2bf(f.z); o.w = f2bf(f.w);
        reinterpret_cast<ushort4*>(dst)[i] = o;
    }
    const float kk = -13.287712379549449f / 32.0f;  // -log2(10000)/32
    for (int idx = blockIdx.x * 256 + threadIdx.x; idx < SEQ * 32; idx += stride) {
        int s = idx >> 5, fi = idx & 31;
        float p = (float)pos[s];
        float ang = p * exp2f((float)fi * kk);
        float sn_, cs_;
        sincosf(ang, &sn_, &cs_);
        csT[idx] = cs_;
        snT[idx] = sn_;
    }
}

// ---------------- bf16 GEMM, fused QKV epilogue (rope + V^T) ----------------
__global__ __launch_bounds__(256) void gemm_qkv(const unsigned short* __restrict__ A,
                                                const unsigned short* __restrict__ B,
                                                unsigned short* __restrict__ outB,
                                                unsigned short* __restrict__ vtp,
                                                const float* __restrict__ csT,
                                                const float* __restrict__ snT,
                                                int M, int N, int K) {
    alignas(16) __shared__ unsigned short a_lds[2][128 * 32];
    alignas(16) __shared__ unsigned short b_lds[2][128 * 32];
    __shared__ unsigned short vtile[4][16][72];
    const int tid = threadIdx.x;
    const int wave = tid >> 6, lane = tid & 63;
    const int l16 = lane & 15, g = lane >> 4;
    const int wr = wave >> 1, wc = wave & 1;

    const int bid = blockIdx.x;
    const int t = (bid & 7) * 96 + (bid >> 3);
    const int bm = t / 24, bn = t % 24;

    const int lrow = lane >> 2;
    const int lcol = (lane & 3) * 8;

    const unsigned short* Ag = A + (size_t)(bm * 128 + lrow) * K + lcol;
    const unsigned short* Bg = B + (size_t)(bn * 128 + lrow) * K + lcol;

    f32x4 acc[4][4] = {};
    const int NS = K / 32;

    auto STAGE = [&](int b, int ks) {
#pragma unroll
        for (int j = 0; j < 2; ++j) {
            int chunk = wave * 2 + j;
            gload16(Ag + (size_t)(chunk * 16) * K + ks * 32, a_lds[b] + chunk * 512);
            gload16(Bg + (size_t)(chunk * 16) * K + ks * 32, b_lds[b] + chunk * 512);
        }
    };

    STAGE(0, 0);

    for (int ks = 0; ks < NS; ++ks) {
        const int cur = ks & 1;
        asm volatile("s_waitcnt vmcnt(0)" ::: "memory");
        __builtin_amdgcn_s_barrier();
        if (ks + 1 < NS) STAGE(cur ^ 1, ks + 1);

        bf16x8 af[4], bfr[4];
#pragma unroll
        for (int m = 0; m < 4; ++m)
            af[m] = *reinterpret_cast<const bf16x8*>(a_lds[cur] + (wr * 64 + m * 16 + l16) * 32 + g * 8);
#pragma unroll
        for (int n = 0; n < 4; ++n)
            bfr[n] = *reinterpret_cast<const bf16x8*>(b_lds[cur] + (wc * 64 + n * 16 + l16) * 32 + g * 8);
        __builtin_amdgcn_s_setprio(1);
#pragma unroll
        for (int m = 0; m < 4; ++m)
#pragma unroll
            for (int n = 0; n < 4; ++n)
                acc[m][n] = __builtin_amdgcn_mfma_f32_16x16x32_bf16(af[m], bfr[n], acc[m][n], 0, 0, 0);
        __builtin_amdgcn_s_setprio(0);
    }

    const float QS = 0.125f * 1.4426950408889634f;
#pragma unroll
    for (int n = 0; n < 4; ++n) {
        const int col = bn * 128 + wc * 64 + n * 16 + l16;
        const int part = col >> 10;
        const int hh = (col >> 6) & 15;
        if (part < 2) {
            const int fi = (col & 63) >> 1;
            const float sc = (part == 0) ? QS : 1.0f;
            const bool odd = (col & 1) != 0;
#pragma unroll
            for (int m = 0; m < 4; ++m)
#pragma unroll
                for (int r = 0; r < 4; ++r) {
                    int row = bm * 128 + wr * 64 + m * 16 + g * 4 + r;
                    float v = acc[m][n][r];
                    float pp = __shfl_xor(v, 1);
                    float cs_ = csT[row * 32 + fi];
                    float sn_ = snT[row * 32 + fi];
                    float out = odd ? (pp * sn_ + v * cs_) : (v * cs_ - pp * sn_);
                    outB[(size_t)((part * HEADS + hh) * SEQ + row) * HD + (col & 63)] = f2bf(out * sc);
                }
        } else {
#pragma unroll
            for (int m = 0; m < 4; ++m)
#pragma unroll
                for (int r = 0; r < 4; ++r)
                    vtile[wave][l16][m * 16 + g * 4 + r] = f2bf(acc[m][n][r]);
#pragma unroll
            for (int dd = 0; dd < 16; ++dd) {
                int dg = ((col & 63) & ~15) + dd;
                vtp[(size_t)(hh * HD + dg) * SEQ + bm * 128 + wr * 64 + lane] =
                    vtile[wave][dd][lane];
            }
        }
    }
}

// ---------------- output GEMM, 128x64 tile ----------------
__global__ __launch_bounds__(256) void gemm_out(const unsigned short* __restrict__ A,
                                                const unsigned short* __restrict__ B,
                                                float* __restrict__ outF,
                                                int M, int N, int K) {
    alignas(16) __shared__ unsigned short a_lds[2][128 * 32];
    alignas(16) __shared__ unsigned short b_lds[2][64 * 32];
    const int tid = threadIdx.x;
    const int wave = tid >> 6, lane = tid & 63;
    const int l16 = lane & 15, g = lane >> 4;
    const int wr = wave >> 1, wc = wave & 1;
    const int bm = blockIdx.x, bn = blockIdx.y;

    const int lrow = lane >> 2;
    const int lcol = (lane & 3) * 8;

    const unsigned short* Ag = A + (size_t)(bm * 128 + lrow) * K + lcol;
    const unsigned short* Bg = B + (size_t)(bn * 64 + lrow) * K + lcol;

    f32x4 acc[4][2] = {};
    const int NS = K / 32;

    auto STAGE = [&](int b, int ks) {
#pragma unroll
        for (int j = 0; j < 2; ++j) {
            int chunk = wave * 2 + j;
            gload16(Ag + (size_t)(chunk * 16) * K + ks * 32, a_lds[b] + chunk * 512);
        }
        gload16(Bg + (size_t)(wave * 16) * K + ks * 32, b_lds[b] + wave * 512);
    };

    STAGE(0, 0);

    for (int ks = 0; ks < NS; ++ks) {
        const int cur = ks & 1;
        asm volatile("s_waitcnt vmcnt(0)" ::: "memory");
        __builtin_amdgcn_s_barrier();
        if (ks + 1 < NS) STAGE(cur ^ 1, ks + 1);

        bf16x8 af[4], bfr[2];
#pragma unroll
        for (int m = 0; m < 4; ++m)
            af[m] = *reinterpret_cast<const bf16x8*>(a_lds[cur] + (wr * 64 + m * 16 + l16) * 32 + g * 8);
#pragma unroll
        for (int n = 0; n < 2; ++n)
            bfr[n] = *reinterpret_cast<const bf16x8*>(b_lds[cur] + (wc * 32 + n * 16 + l16) * 32 + g * 8);
        __builtin_amdgcn_s_setprio(1);
#pragma unroll
        for (int m = 0; m < 4; ++m)
#pragma unroll
            for (int n = 0; n < 2; ++n)
                acc[m][n] = __builtin_amdgcn_mfma_f32_16x16x32_bf16(af[m], bfr[n], acc[m][n], 0, 0, 0);
        __builtin_amdgcn_s_setprio(0);
    }

#pragma unroll
    for (int m = 0; m < 4; ++m)
#pragma unroll
        for (int n = 0; n < 2; ++n)
#pragma unroll
            for (int r = 0; r < 4; ++r) {
                int row = bm * 128 + wr * 64 + m * 16 + g * 4 + r;
                int col = bn * 64 + wc * 32 + n * 16 + l16;
                outF[(size_t)row * N + col] = acc[m][n][r];
            }
}

// ---------------- causal flash attention (queue + up-to-4-piece split-K) ----------------
__device__ __forceinline__ int slot_of(int qt, int p) {
    if (qt <= 13) return (qt - 5) * 2 + p;          // qt5..13 -> 0..17
    return 18 + (qt - 14) * 4 + p;                  // qt14 -> 18..21, qt15 -> 22..25
}

__global__ __launch_bounds__(512) void attn_kernel(const unsigned short* __restrict__ qkv,
                                                   const unsigned short* __restrict__ vt,
                                                   unsigned short* __restrict__ attnout,
                                                   int* __restrict__ qcnt,
                                                   unsigned short* __restrict__ pO,
                                                   float* __restrict__ lmf) {
    const int xcd = blockIdx.x & 7;
    const int tid = threadIdx.x;
    const int wave = tid >> 6, lane = tid & 63;
    const int l32 = lane & 31, hi = lane >> 5;

    alignas(16) __shared__ unsigned short k_lds[2][128 * 64];
    alignas(16) __shared__ unsigned short v_lds[2][2][64 * 64];
    __shared__ int slot_sh;

    const int rsw = (l32 & 7) << 4;

    for (;;) {
        if (tid == 0) slot_sh = atomicAdd(&qcnt[xcd], 1);
        __syncthreads();
        const int t = slot_sh;
        __syncthreads();
        if (t >= 62) break;

        const int hloc = t & 1;
        const unsigned char e = TASKS[t >> 1];
        const int qtile = e & 31;
        const int piece = (e >> 5) & 3;
        const bool isSplit = (e & 0x80) != 0;
        const int T = 2 * qtile + 2;
        int k0, k1;
        if (!isSplit) { k0 = 0; k1 = T; }
        else if (qtile <= 13) {
            int Hh = (T + 1) >> 1;
            k0 = piece ? Hh : 0; k1 = piece ? T : Hh;
        } else {
            int ch = (T + 3) >> 2;
            k0 = piece * ch; k1 = min(T, k0 + ch);
        }
        const int h = xcd * 2 + hloc;

        const unsigned short* Qg = qkv + (size_t)((0 * HEADS + h) * SEQ) * HD;
        const unsigned short* Kg = qkv + (size_t)((1 * HEADS + h) * SEQ) * HD;
        const unsigned short* VTg = vt + (size_t)h * HD * SEQ;

        const int qbase = qtile * 256 + wave * 32;
        const int qrow = qbase + l32;

        bf16x8 qf[4];
#pragma unroll
        for (int dg = 0; dg < 4; ++dg)
            qf[dg] = *reinterpret_cast<const bf16x8*>(Qg + (size_t)qrow * HD + dg * 16 + hi * 8);

        f32x16 oa[2] = {};
        float m_r = -1e30f, l_r = 0.f;

        auto STAGE = [&](int b, int kt) {
#pragma unroll
            for (int i = 0; i < 2; ++i) {
                int base = wave * 2048 + i * 1024;
                int byte = base + lane * 16;
                int krow = byte >> 7;
                int kc8 = ((byte >> 4) & 7) ^ (krow & 7);
                gload16(Kg + (size_t)(kt * 128 + krow) * HD + kc8 * 8, (char*)k_lds[b] + base);
                int fr = byte >> 7;
                int h64 = fr >> 6, vd = fr & 63;
                int vc8 = ((byte >> 4) & 7) ^ (vd & 7);
                gload16(VTg + (size_t)vd * SEQ + kt * 128 + h64 * 64 + vc8 * 8,
                        (char*)v_lds[b] + base);
            }
        };

        STAGE(0, k0);

        for (int kt = k0; kt < k1; ++kt) {
            const int cur = (kt - k0) & 1;
            asm volatile("s_waitcnt vmcnt(0)" ::: "memory");
            __builtin_amdgcn_s_barrier();
            if (kt + 1 < k1) STAGE(cur ^ 1, kt + 1);

#pragma unroll
            for (int hh = 0; hh < 2; ++hh) {
                if (hh && (kt * 128 + 64) > (qbase + 31)) break;

                f32x16 s[2] = {};
                __builtin_amdgcn_s_setprio(1);
#pragma unroll
                for (int g = 0; g < 2; ++g) {
                    if (kt * 128 + hh * 64 + g * 32 > qbase + 31) continue;  // fully masked group
                    int row = hh * 64 + g * 32 + l32;
#pragma unroll
                    for (int dg = 0; dg < 4; ++dg) {
                        bf16x8 kf = *reinterpret_cast<const bf16x8*>(
                            (char*)k_lds[cur] + row * 128 + ((dg * 32 + hi * 16) ^ rsw));
                        s[g] = __builtin_amdgcn_mfma_f32_32x32x16_bf16(kf, qf[dg], s[g], 0, 0, 0);
                    }
                }
                __builtin_amdgcn_s_setprio(0);

                if (kt * 128 + hh * 64 + 63 > qbase) {
#pragma unroll
                    for (int g = 0; g < 2; ++g)
#pragma unroll
                        for (int r = 0; r < 16; ++r) {
                            int kv = kt * 128 + hh * 64 + g * 32 + (r & 3) + 8 * (r >> 2) + 4 * hi;
                            if (kv > qrow) s[g][r] = -1e30f;
                        }
                }

                float ma = -1e30f, mb = -1e30f, mc = -1e30f, md = -1e30f;
#pragma unroll
                for (int r = 0; r < 16; r += 4) {
                    ma = fmaxf(ma, fmaxf(s[0][r], s[1][r]));
                    mb = fmaxf(mb, fmaxf(s[0][r + 1], s[1][r + 1]));
                    mc = fmaxf(mc, fmaxf(s[0][r + 2], s[1][r + 2]));
                    md = fmaxf(md, fmaxf(s[0][r + 3], s[1][r + 3]));
                }
                float mx = fmaxf(fmaxf(ma, mb), fmaxf(mc, md));
                mx = fmaxf(mx, __shfl_xor(mx, 32));

                if (__any(mx > m_r + 8.0f)) {
                    float mnew = fmaxf(m_r, mx);
                    float alpha = __builtin_amdgcn_exp2f(m_r - mnew);
                    m_r = mnew;
#pragma unroll
                    for (int r = 0; r < 16; ++r) { oa[0][r] *= alpha; oa[1][r] *= alpha; }
                    l_r *= alpha;
                }

#pragma unroll
                for (int g = 0; g < 2; ++g)
#pragma unroll
                    for (int r = 0; r < 16; ++r) s[g][r] = __builtin_amdgcn_exp2f(s[g][r] - m_r);

                float ra = 0.f, rb = 0.f;
#pragma unroll
                for (int r = 0; r < 16; r += 2) {
                    ra += s[0][r] + s[1][r];
                    rb += s[0][r + 1] + s[1][r + 1];
                }
                float rs = ra + rb;
                rs += __shfl_xor(rs, 32);
                l_r += rs;

                __builtin_amdgcn_s_setprio(1);
#pragma unroll
                for (int g = 0; g < 2; ++g) {
                    u32x4 pfw[2];
#pragma unroll
                    for (int u = 0; u < 2; ++u) {
                        unsigned wA = cvt_pk_bf16(s[g][8 * u + 0], s[g][8 * u + 1]);
                        unsigned wC = cvt_pk_bf16(s[g][8 * u + 2], s[g][8 * u + 3]);
                        unsigned wB = cvt_pk_bf16(s[g][8 * u + 4], s[g][8 * u + 5]);
                        unsigned wD = cvt_pk_bf16(s[g][8 * u + 6], s[g][8 * u + 7]);
                        unsigned wAx = __shfl_xor((int)wA, 32), wBx = __shfl_xor((int)wB, 32);
                        unsigned wCx = __shfl_xor((int)wC, 32), wDx = __shfl_xor((int)wD, 32);
                        pfw[u][0] = hi ? wBx : wA;
                        pfw[u][1] = hi ? wDx : wC;
                        pfw[u][2] = hi ? wB : wAx;
                        pfw[u][3] = hi ? wD : wCx;
                    }
#pragma unroll
                    for (int u = 0; u < 2; ++u) {
                        bf16x8 pf = __builtin_bit_cast(bf16x8, pfw[u]);
                        int ks = g * 2 + u;
#pragma unroll
                        for (int dg = 0; dg < 2; ++dg) {
                            bf16x8 vf = *reinterpret_cast<const bf16x8*>(
                                (char*)v_lds[cur][hh] + (dg * 32 + l32) * 128 + ((ks * 32 + hi * 16) ^ rsw));
                            oa[dg] = __builtin_amdgcn_mfma_f32_32x32x16_bf16(vf, pf, oa[dg], 0, 0, 0);
                        }
                    }
                }
                __builtin_amdgcn_s_setprio(0);
            }
        }

        const int ql = wave * 32 + l32;
        if (isSplit) {
            int sidx = h * 26 + slot_of(qtile, piece);
            unsigned short* Op = pO + (size_t)sidx * 16384;
#pragma unroll
            for (int dg = 0; dg < 2; ++dg)
#pragma unroll
                for (int rq = 0; rq < 4; ++rq) {
                    ushort4 ov;
                    ov.x = f2bf(oa[dg][4 * rq + 0]);
                    ov.y = f2bf(oa[dg][4 * rq + 1]);
                    ov.z = f2bf(oa[dg][4 * rq + 2]);
                    ov.w = f2bf(oa[dg][4 * rq + 3]);
                    *reinterpret_cast<ushort4*>(Op + ql * 64 + dg * 32 + 8 * rq + 4 * hi) = ov;
                }
            if (hi == 0) {
                lmf[sidx * 512 + ql] = l_r;
                lmf[sidx * 512 + 256 + ql] = m_r;
            }
        } else {
            float inv = 1.0f / l_r;
            unsigned short* orow = attnout + (size_t)(qtile * 256 + ql) * DMODEL + h * HD;
#pragma unroll
            for (int dg = 0; dg < 2; ++dg)
#pragma unroll
                for (int rq = 0; rq < 4; ++rq) {
                    ushort4 ov;
                    ov.x = f2bf(oa[dg][4 * rq + 0] * inv);
                    ov.y = f2bf(oa[dg][4 * rq + 1] * inv);
                    ov.z = f2bf(oa[dg][4 * rq + 2] * inv);
                    ov.w = f2bf(oa[dg][4 * rq + 3] * inv);
                    *reinterpret_cast<ushort4*>(orow + dg * 32 + 8 * rq + 4 * hi) = ov;
                }
        }
    }
}

// ---------------- merge K-piece partials (qt5..13: 2 pieces; qt14,15: 4) ----------------
__global__ __launch_bounds__(256) void merge_kernel(const unsigned short* __restrict__ pO,
                                                    const float* __restrict__ lmf,
                                                    unsigned short* __restrict__ attnout) {
    int idx = blockIdx.x * 256 + threadIdx.x;   // 16 h x 11 split-qt x 256 q x 8 d8
    if (idx >= 16 * 11 * 2048) return;
    int h = idx / (11 * 2048);
    int r = idx % (11 * 2048);
    int qti = r >> 11;          // 0..10 -> qtile 5..15
    int rr = r & 2047;
    int q = rr >> 3, d8 = rr & 7;
    int qtile = qti + 5;
    int np = (qtile >= 14) ? 4 : 2;
    int s0 = h * 26 + slot_of(qtile, 0);

    float m = -1e30f;
#pragma unroll 4
    for (int p = 0; p < np; ++p) m = fmaxf(m, lmf[(s0 + p) * 512 + 256 + q]);
    float L = 0.f, c[4];
#pragma unroll 4
    for (int p = 0; p < np; ++p) {
        float lp = lmf[(s0 + p) * 512 + q];
        float mp = lmf[(s0 + p) * 512 + 256 + q];
        c[p] = __builtin_amdgcn_exp2f(mp - m);
        L += lp * c[p];
    }
    float invL = 1.0f / L;

    float accv[8] = {};
#pragma unroll 4
    for (int p = 0; p < np; ++p) {
        short8 v = *reinterpret_cast<const short8*>(pO + (size_t)(s0 + p) * 16384 + q * 64 + d8 * 8);
        float w = c[p] * invL;
#pragma unroll
        for (int j = 0; j < 8; ++j) accv[j] += bf2f((unsigned short)v[j]) * w;
    }
    short8 o;
#pragma unroll
    for (int j = 0; j < 8; ++j) o[j] = (short)f2bf(accv[j]);
    *reinterpret_cast<short8*>(attnout + (size_t)(qtile * 256 + q) * DMODEL + h * HD + d8 * 8) = o;
}

extern "C" void kernel_launch(void* const* d_in, const int* in_sizes, int n_in,
                              void* d_out, int out_size, void* d_ws, size_t ws_size,
                              hipStream_t stream) {
    const float* x = (const float*)d_in[0];
    const int* pos = (const int*)d_in[1];
    const float* wqkv = (const float*)d_in[2];
    const float* wo = (const float*)d_in[3];
    float* out = (float*)d_out;

    unsigned short* xb = (unsigned short*)d_ws;                       // 8MB
    unsigned short* wqkvb = xb + (size_t)SEQ * DMODEL;                // 6MB
    unsigned short* wob = wqkvb + (size_t)NQKV * DMODEL;              // 2MB
    unsigned short* qkvp = wob + (size_t)DMODEL * DMODEL;             // 24MB
    unsigned short* vtp = qkvp + (size_t)2 * HEADS * SEQ * HD;
    float* csT = (float*)(qkvp + (size_t)3 * HEADS * SEQ * HD);       // 512KB
    float* snT = csT + SEQ * 32;                                      // 512KB
    unsigned short* attnb = (unsigned short*)(snT + SEQ * 32);        // 8MB
    int* qcnt = (int*)(attnb + (size_t)SEQ * DMODEL);                 // 64B, OUTSIDE f2bf dst

    // split-K scratch in xb/wqkvb (dead after gemm_qkv; written only by attn)
    char* sbase = (char*)d_ws;
    unsigned short* pO = (unsigned short*)sbase;                      // 13MB
    float* lmf = (float*)(sbase + (size_t)416 * 32768);               // 832KB

    f2bf_all<<<2048, 256, 0, stream>>>(x, wqkv, wo, pos, xb, csT, snT, qcnt);

    gemm_qkv<<<768, 256, 0, stream>>>(xb, wqkvb, qkvp, vtp, csT, snT, SEQ, NQKV, DMODEL);

    attn_kernel<<<512, 512, 0, stream>>>(qkvp, vtp, attnb, qcnt, pO, lmf);
    merge_kernel<<<(16 * 11 * 2048 + 255) / 256, 256, 0, stream>>>(pO, lmf, attnb);

    dim3 g2(SEQ / 128, DMODEL / 64);
    gemm_out<<<g2, 256, 0, stream>>>(attnb, wob, out, SEQ, DMODEL, DMODEL);
}